// Round 8
// baseline (274.919 us; speedup 1.0000x reference)
//
#include <hip/hip_runtime.h>
#include <hip/hip_bf16.h>

// Problem constants: B=2, L=2048, D=1024, H=16, d_k=64
#define Hh 16
#define Ll 2048
#define Dd 1024
#define DK 64
#define Mm 4096  // B*L
#define Kk 1024
#define Nn 1024

typedef short bf16x8 __attribute__((ext_vector_type(8)));
typedef float f32x4 __attribute__((ext_vector_type(4)));

static __device__ __forceinline__ unsigned short f2bf(float f) {
    union { __hip_bfloat16 b; unsigned short u; } cv;
    cv.b = __float2bfloat16(f);
    return cv.u;
}

// truncate-pack two fp32 -> bf16x2 (a in low half). Single v_perm_b32.
static __device__ __forceinline__ unsigned packtr(float a, float b) {
    return __builtin_amdgcn_perm(__builtin_bit_cast(unsigned, b),
                                 __builtin_bit_cast(unsigned, a), 0x07060302u);
}

// round-half-up pack: int-add 0x8000 to the magnitude (sign-magnitude fp32 ->
// rounds |x| half away from zero; bias-free for symmetric data), then perm.
static __device__ __forceinline__ unsigned packrnd(float a, float b) {
    const unsigned ua = __builtin_bit_cast(unsigned, a) + 0x8000u;
    const unsigned ub = __builtin_bit_cast(unsigned, b) + 0x8000u;
    return __builtin_amdgcn_perm(ub, ua, 0x07060302u);
}

// 8 fp32 (two float4) -> bf16x8 fragment, round-half-up
static __device__ __forceinline__ bf16x8 cvt8(const float4 f0, const float4 f1) {
    bf16x8 r;
    ((unsigned*)&r)[0] = packrnd(f0.x, f0.y);
    ((unsigned*)&r)[1] = packrnd(f0.z, f0.w);
    ((unsigned*)&r)[2] = packrnd(f1.x, f1.y);
    ((unsigned*)&r)[3] = packrnd(f1.z, f1.w);
    return r;
}

static __device__ __forceinline__ float fexp2(float x) {
    return __builtin_amdgcn_exp2f(x);  // single v_exp_f32
}

// async global->LDS, 16B/lane. LDS dest = wave-uniform base + lane*16 (HW rule).
static __device__ __forceinline__ void glds16(const ushort* g, ushort* l) {
    __builtin_amdgcn_global_load_lds((const __attribute__((address_space(1))) unsigned int*)g,
                                     (__attribute__((address_space(3))) unsigned int*)l,
                                     16, 0, 0);
}
static __device__ __forceinline__ void glds16f(const float* g, float* l) {
    __builtin_amdgcn_global_load_lds((const __attribute__((address_space(1))) unsigned int*)g,
                                     (__attribute__((address_space(3))) unsigned int*)l,
                                     16, 0, 0);
}

// ---------------- fused QKV projection GEMM (fp32 in, BK=32, swizzled fp32 panels) ----------------
// C = A @ W^T + bias, A/W read directly in fp32 (no separate cast kernel).
// LDS panels [128 rows][8 granules x 4 fp32], granule position p = G ^ (row&7)
// -> staging stays 16B-contiguous per lane AND fragment b128 reads spread all 32 banks.
// z=0: Q (pre-scaled by 0.125*log2e) -> [BH,L,64]; z=1: K -> [BH,L,64];
// z=2: V -> LDS-transposed [BH,64,L].
__global__ __launch_bounds__(256) void gemm_qkv(
    const float* __restrict__ A0, const float* __restrict__ A1, const float* __restrict__ A2,
    const float* __restrict__ W0, const float* __restrict__ W1, const float* __restrict__ W2,
    const float* __restrict__ b0, const float* __restrict__ b1, const float* __restrict__ b2,
    ushort* __restrict__ O0, ushort* __restrict__ O1, ushort* __restrict__ OVt) {
    __shared__ __align__(16) float Asf[128 * 32];  // 16KB
    __shared__ __align__(16) float Bsf[128 * 32];  // 16KB
    const int z = blockIdx.z;
    const float* A = (z == 0) ? A0 : (z == 1) ? A1 : A2;
    const float* W = (z == 0) ? W0 : (z == 1) ? W1 : W2;
    const float* bias = (z == 0) ? b0 : (z == 1) ? b1 : b2;

    const int t = threadIdx.x;
    const int wave = t >> 6, lane = t & 63;
    const int quad = lane >> 4, l15 = lane & 15;
    const int brow = blockIdx.y * 128, bcol = blockIdx.x * 128;
    const int wr = (wave >> 1) * 64, wc = (wave & 1) * 64;

    // staging geometry: lane covers row rlane (of 8), swizzled granule G
    const int rlane = lane >> 3;                       // 0..7
    const int G4 = (((lane & 7) ^ (rlane & 7)) << 2);  // granule * 4 floats
    const int x7 = l15 & 7;                            // fragment-row swizzle key

    f32x4 acc[4][4] = {};

    for (int k0 = 0; k0 < Kk; k0 += 32) {
        __syncthreads();  // all waves done reading previous tile
#pragma unroll
        for (int c = 0; c < 4; c++) {
            const int r0 = wave * 32 + c * 8;  // tile row base for this glds
            glds16f(A + (size_t)(brow + r0 + rlane) * Kk + k0 + G4, Asf + r0 * 32);
            glds16f(W + (size_t)(bcol + r0 + rlane) * Kk + k0 + G4, Bsf + r0 * 32);
        }
        __syncthreads();  // vmcnt(0) drain -> LDS ready

        bf16x8 af[4], bfr[4];
#pragma unroll
        for (int i = 0; i < 4; i++) {
            const int m = wr + i * 16 + l15;
            const float4 f0 = *(const float4*)(Asf + m * 32 + (((2 * quad) ^ x7) << 2));
            const float4 f1 = *(const float4*)(Asf + m * 32 + (((2 * quad + 1) ^ x7) << 2));
            af[i] = cvt8(f0, f1);
        }
#pragma unroll
        for (int j = 0; j < 4; j++) {
            const int m = wc + j * 16 + l15;
            const float4 f0 = *(const float4*)(Bsf + m * 32 + (((2 * quad) ^ x7) << 2));
            const float4 f1 = *(const float4*)(Bsf + m * 32 + (((2 * quad + 1) ^ x7) << 2));
            bfr[j] = cvt8(f0, f1);
        }
#pragma unroll
        for (int i = 0; i < 4; i++)
#pragma unroll
            for (int j = 0; j < 4; j++)
                acc[i][j] = __builtin_amdgcn_mfma_f32_16x16x32_bf16(af[i], bfr[j], acc[i][j], 0, 0, 0);
    }

    ushort* SMu = (ushort*)Asf;  // reuse LDS for epilogues

    // C/D layout: row = quad*4+r, col = l15
    if (z < 2) {
        // Repack each wave's 64x64 tile (one head) through LDS -> coalesced 16B stores.
        ushort* Out = (z == 0) ? O0 : O1;
        const float oscl = (z == 0) ? 0.18033688f : 1.0f;  // 0.125*log2(e) folded into Q
        const int b = brow >> 11;
        const int lbase = (brow & 2047) + wr;
        const int h = (bcol + wc) >> 6;           // one head per wave
        ushort* T = SMu + wave * 1280;            // [16][80] per wave (odd dword stride)
        __syncthreads();                          // staging reads done; safe to reuse
#pragma unroll
        for (int i = 0; i < 4; i++) {
#pragma unroll
            for (int j = 0; j < 4; j++) {
                const float bv = bias[bcol + wc + j * 16 + l15];
#pragma unroll
                for (int r = 0; r < 4; r++)
                    T[(quad * 4 + r) * 80 + j * 16 + l15] = f2bf((acc[i][j][r] + bv) * oscl);
            }
            const int r8 = lane >> 3, c8 = lane & 7;
#pragma unroll
            for (int pass = 0; pass < 2; pass++) {
                const uint4 val = *(const uint4*)(T + (pass * 8 + r8) * 80 + c8 * 8);
                const int l = lbase + i * 16 + pass * 8 + r8;
                *(uint4*)(Out + ((size_t)(b * Hh + h) * Ll + l) * DK + c8 * 8) = val;
            }
        }
    } else {
        // LDS transpose epilogue: emit V^T [BH, 64, L] with coalesced 16B stores.
        ushort* T = SMu;  // T[32][136]
        const int b = brow >> 11;
        const int lbase = brow & 2047;
        const int npr = (wave & 1) * 16 + l15;
#pragma unroll
        for (int j = 0; j < 4; j++) {
            __syncthreads();
            const float bv = bias[bcol + wc + j * 16 + l15];
#pragma unroll
            for (int i = 0; i < 4; i++)
#pragma unroll
                for (int r = 0; r < 4; r++) {
                    const int m = wr + i * 16 + quad * 4 + r;
                    T[npr * 136 + m] = f2bf(acc[i][j][r] + bv);
                }
            __syncthreads();
#pragma unroll
            for (int cc = 0; cc < 2; cc++) {
                const int idx = t + cc * 256;
                const int ni = idx >> 4;
                const int ms = idx & 15;
                const int n = bcol + (ni >> 4) * 64 + j * 16 + (ni & 15);
                const int hh = n >> 6, dk = n & 63;
                uint4 val = *(const uint4*)(T + ni * 136 + ms * 8);
                *(uint4*)(OVt + ((size_t)(b * Hh + hh) * DK + dk) * Ll + lbase + ms * 8) = val;
            }
        }
    }
}

// ---------------- fused attention (unchanged from R6) ----------------
__global__ __launch_bounds__(256) void attn_kernel(const ushort* __restrict__ Q,
                                                   const ushort* __restrict__ Kp,
                                                   const ushort* __restrict__ Vt,
                                                   ushort* __restrict__ Oout,
                                                   const int* __restrict__ masksize) {
    __shared__ __align__(16) ushort Ks[2 * 128 * 32];  // 16KB
    __shared__ __align__(16) ushort Vs[64 * 128];      // 16KB
    const int t = threadIdx.x;
    const int wave = t >> 6, lane = t & 63;
    const int quad = lane >> 4, l15 = lane & 15;
    const int bx = blockIdx.x;
    const int bh = bx & 31, qc = bx >> 5;
    const int q0w = qc * 128 + wave * 32;
    const int half = masksize[0] >> 1;
    const unsigned wid = (unsigned)(2 * half);

    const ushort* Qb = Q + (size_t)bh * (Ll * DK);
    const ushort* Kb = Kp + (size_t)bh * (Ll * DK);
    const ushort* Vb = Vt + (size_t)bh * (DK * Ll);

    const bf16x8 qA0 = *(const bf16x8*)(Qb + (size_t)(q0w + l15) * DK + quad * 8);
    const bf16x8 qA1 = *(const bf16x8*)(Qb + (size_t)(q0w + l15) * DK + 32 + quad * 8);
    const bf16x8 qB0 = *(const bf16x8*)(Qb + (size_t)(q0w + 16 + l15) * DK + quad * 8);
    const bf16x8 qB1 = *(const bf16x8*)(Qb + (size_t)(q0w + 16 + l15) * DK + 32 + quad * 8);

    const float C2IN  = (1.0f - 24.0f) * 1.44269504088896f;
    const float C2OUT = -24.0f * 1.44269504088896f;
    const float E1 = 2.718281828f;

    bf16x8 onesf;
#pragma unroll
    for (int j = 0; j < 8; j++) onesf[j] = (short)0x3F80;

    f32x4 OA[4] = {}, OB[4] = {};
    f32x4 SA = {}, SB = {};

    const int krow = lane >> 2;
    const int kcol8 = (lane & 3) * 8;
    const int vdl = lane >> 4;
    const int vg0 = 2 * (lane & 15);

    for (int kt = 0; kt < Ll; kt += 128) {
        __syncthreads();
        if (wave < 2) {
            const int cbase = wave * 4;
#pragma unroll
            for (int c = 0; c < 4; c++)
#pragma unroll
                for (int pan = 0; pan < 2; pan++)
                    glds16(Kb + (size_t)(kt + (cbase + c) * 16 + krow) * DK + pan * 32 + kcol8,
                           Ks + (pan * 128 + (cbase + c) * 16) * 32);
        } else {
            const int sb = (wave - 2) * 8;
#pragma unroll
            for (int i = 0; i < 8; i++) {
                const int sidx = sb + i;
                const int d = sidx * 4 + vdl;
                const int g0 = vg0 ^ (d & 30);
                glds16(Vb + (size_t)d * Ll + kt + g0 * 4, Vs + sidx * 512);
            }
        }
        __syncthreads();

        const int qlo = q0w, qhi = q0w + 31;
        const bool allout = (kt + 127 < qlo - half) || (kt > qhi + half);
        const bool allin  = (kt >= qhi - half) && (kt + 127 <= qlo + half);
        const bool uniform = allin || allout;
        const float cinit = allin ? C2IN : C2OUT;
        f32x4 cvec = {cinit, cinit, cinit, cinit};

#pragma unroll
        for (int s = 0; s < 4; s++) {
            const bf16x8 kf00 = *(const bf16x8*)(Ks + ((2 * s) * 16 + l15) * 32 + quad * 8);
            const bf16x8 kf01 = *(const bf16x8*)(Ks + 4096 + ((2 * s) * 16 + l15) * 32 + quad * 8);
            const bf16x8 kf10 = *(const bf16x8*)(Ks + ((2 * s + 1) * 16 + l15) * 32 + quad * 8);
            const bf16x8 kf11 = *(const bf16x8*)(Ks + 4096 + ((2 * s + 1) * 16 + l15) * 32 + quad * 8);
            f32x4 zA0 = __builtin_amdgcn_mfma_f32_16x16x32_bf16(kf00, qA0, cvec, 0, 0, 0);
            zA0 = __builtin_amdgcn_mfma_f32_16x16x32_bf16(kf01, qA1, zA0, 0, 0, 0);
            f32x4 zA1 = __builtin_amdgcn_mfma_f32_16x16x32_bf16(kf10, qA0, cvec, 0, 0, 0);
            zA1 = __builtin_amdgcn_mfma_f32_16x16x32_bf16(kf11, qA1, zA1, 0, 0, 0);
            f32x4 zB0 = __builtin_amdgcn_mfma_f32_16x16x32_bf16(kf00, qB0, cvec, 0, 0, 0);
            zB0 = __builtin_amdgcn_mfma_f32_16x16x32_bf16(kf01, qB1, zB0, 0, 0, 0);
            f32x4 zB1 = __builtin_amdgcn_mfma_f32_16x16x32_bf16(kf10, qB0, cvec, 0, 0, 0);
            zB1 = __builtin_amdgcn_mfma_f32_16x16x32_bf16(kf11, qB1, zB1, 0, 0, 0);

            float pA[8], pB[8];
            if (uniform) {
#pragma unroll
                for (int g = 0; g < 2; g++)
#pragma unroll
                    for (int r = 0; r < 4; r++) {
                        pA[g * 4 + r] = fexp2(g ? zA1[r] : zA0[r]);
                        pB[g * 4 + r] = fexp2(g ? zB1[r] : zB0[r]);
                    }
            } else {
                const int kb = kt + s * 32 + quad * 4 + half;
#pragma unroll
                for (int g = 0; g < 2; g++)
#pragma unroll
                    for (int r = 0; r < 4; r++) {
                        const unsigned ttA = (unsigned)(kb + g * 16 + r - (q0w + l15));
                        const unsigned ttB = (unsigned)(kb + g * 16 + r - (q0w + 16 + l15));
                        pA[g * 4 + r] = fexp2(g ? zA1[r] : zA0[r]) * (ttA <= wid ? E1 : 1.0f);
                        pB[g * 4 + r] = fexp2(g ? zB1[r] : zB0[r]) * (ttB <= wid ? E1 : 1.0f);
                    }
            }

            bf16x8 pfA, pfB;
            ((unsigned*)&pfA)[0] = packtr(pA[0], pA[1]);
            ((unsigned*)&pfA)[1] = packtr(pA[2], pA[3]);
            ((unsigned*)&pfA)[2] = packtr(pA[4], pA[5]);
            ((unsigned*)&pfA)[3] = packtr(pA[6], pA[7]);
            ((unsigned*)&pfB)[0] = packtr(pB[0], pB[1]);
            ((unsigned*)&pfB)[1] = packtr(pB[2], pB[3]);
            ((unsigned*)&pfB)[2] = packtr(pB[4], pB[5]);
            ((unsigned*)&pfB)[3] = packtr(pB[6], pB[7]);

            SA = __builtin_amdgcn_mfma_f32_16x16x32_bf16(pfA, onesf, SA, 0, 0, 0);
            SB = __builtin_amdgcn_mfma_f32_16x16x32_bf16(pfB, onesf, SB, 0, 0, 0);

#pragma unroll
            for (int i = 0; i < 4; i++) {
                const int d = i * 16 + l15;
                const int x4 = (d & 30) * 4;
                const int bi = d * 128;
                const ushort4 v1 = *(const ushort4*)(Vs + bi + (((s * 8 + quad) * 4) ^ x4));
                const ushort4 v2 = *(const ushort4*)(Vs + bi + (((s * 8 + 4 + quad) * 4) ^ x4));
                bf16x8 vc;
                *(ushort4*)&vc = v1;
                *((ushort4*)&vc + 1) = v2;
                OA[i] = __builtin_amdgcn_mfma_f32_16x16x32_bf16(pfA, vc, OA[i], 0, 0, 0);
                OB[i] = __builtin_amdgcn_mfma_f32_16x16x32_bf16(pfB, vc, OB[i], 0, 0, 0);
            }
        }
    }

    float liA[4], liB[4];
#pragma unroll
    for (int r = 0; r < 4; r++) {
        liA[r] = 1.0f / SA[r];
        liB[r] = 1.0f / SB[r];
    }

    const int b = bh >> 4, h = bh & 15;
#pragma unroll
    for (int i = 0; i < 4; i++)
#pragma unroll
        for (int r = 0; r < 4; r++) {
            const int qa = q0w + quad * 4 + r;
            Oout[((size_t)b * Ll + qa) * Dd + h * DK + i * 16 + l15] = f2bf(OA[i][r] * liA[r]);
            Oout[((size_t)b * Ll + qa + 16) * Dd + h * DK + i * 16 + l15] = f2bf(OB[i][r] * liB[r]);
        }
}

// ---------------- output projection GEMM (bf16 A, fp32 W swizzled, BK=32) ----------------
// 64x128 tile, grid (8,64) = 512 blocks = 2/CU, fp32 out + bias.
__global__ __launch_bounds__(256) void gemm_o(const ushort* __restrict__ A,
                                              const float* __restrict__ W,
                                              const float* __restrict__ bias,
                                              float* __restrict__ Out) {
    __shared__ __align__(16) ushort As[64 * 32];  // 4KB bf16
    __shared__ __align__(16) float Bsf[128 * 32]; // 16KB fp32, swizzled granules
    const int t = threadIdx.x;
    const int wave = t >> 6, lane = t & 63;
    const int quad = lane >> 4, l15 = lane & 15;
    const int brow = blockIdx.y * 64, bcol = blockIdx.x * 128;
    const int wr = (wave >> 1) * 32, wc = (wave & 1) * 64;
    const int gr = wave * 16 + (lane >> 2);  // A staging (bf16): 4 lanes/row
    const int gc = (lane & 3) * 8;
    const int rlane = lane >> 3;             // W staging (fp32): 8 lanes/row
    const int G4 = (((lane & 7) ^ (rlane & 7)) << 2);
    const int x7 = l15 & 7;

    f32x4 acc[2][4] = {};

    for (int k0 = 0; k0 < Kk; k0 += 32) {
        __syncthreads();
        glds16(A + (size_t)(brow + gr) * Kk + k0 + gc, As + wave * 512);
#pragma unroll
        for (int c = 0; c < 4; c++) {
            const int r0 = wave * 32 + c * 8;
            glds16f(W + (size_t)(bcol + r0 + rlane) * Kk + k0 + G4, Bsf + r0 * 32);
        }
        __syncthreads();

        bf16x8 af[2], bfr[4];
#pragma unroll
        for (int i = 0; i < 2; i++)
            af[i] = *(const bf16x8*)(As + (wr + i * 16 + l15) * 32 + quad * 8);
#pragma unroll
        for (int j = 0; j < 4; j++) {
            const int m = wc + j * 16 + l15;
            const float4 f0 = *(const float4*)(Bsf + m * 32 + (((2 * quad) ^ x7) << 2));
            const float4 f1 = *(const float4*)(Bsf + m * 32 + (((2 * quad + 1) ^ x7) << 2));
            bfr[j] = cvt8(f0, f1);
        }
#pragma unroll
        for (int i = 0; i < 2; i++)
#pragma unroll
            for (int j = 0; j < 4; j++)
                acc[i][j] = __builtin_amdgcn_mfma_f32_16x16x32_bf16(af[i], bfr[j], acc[i][j], 0, 0, 0);
    }

#pragma unroll
    for (int i = 0; i < 2; i++)
#pragma unroll
        for (int j = 0; j < 4; j++) {
            const int n = bcol + wc + j * 16 + l15;
            const float bv = bias[n];
#pragma unroll
            for (int r = 0; r < 4; r++) {
                const int m = brow + wr + i * 16 + quad * 4 + r;
                Out[(size_t)m * Nn + n] = acc[i][j][r] + bv;
            }
        }
}

// ---------------- launch ----------------
extern "C" void kernel_launch(void* const* d_in, const int* in_sizes, int n_in,
                              void* d_out, int out_size, void* d_ws, size_t ws_size,
                              hipStream_t stream) {
    const float* query = (const float*)d_in[0];
    const float* key   = (const float*)d_in[1];
    const float* value = (const float*)d_in[2];
    const float* Wq = (const float*)d_in[3];
    const float* bq = (const float*)d_in[4];
    const float* Wk = (const float*)d_in[5];
    const float* bk = (const float*)d_in[6];
    const float* Wv = (const float*)d_in[7];
    const float* bv = (const float*)d_in[8];
    const float* Wo = (const float*)d_in[9];
    const float* bo = (const float*)d_in[10];
    const int* masksize = (const int*)d_in[11];

    char* ws = (char*)d_ws;
    const size_t MB = 1024 * 1024;
    ushort* Qp = (ushort*)(ws + 0 * MB);   // [BH, L, 64] bf16, pre-scaled by 0.125*log2e
    ushort* Kp = (ushort*)(ws + 8 * MB);   // [BH, L, 64] bf16
    ushort* Vt = (ushort*)(ws + 16 * MB);  // [BH, 64, L] bf16
    ushort* AO = (ushort*)(ws + 24 * MB);  // [4096, 1024] bf16

    gemm_qkv<<<dim3(8, 32, 3), 256, 0, stream>>>(query, key, value,
                                                 Wq, Wk, Wv,
                                                 bq, bk, bv,
                                                 Qp, Kp, Vt);

    attn_kernel<<<512, 256, 0, stream>>>(Qp, Kp, Vt, AO, masksize);

    gemm_o<<<dim3(8, 64), 256, 0, stream>>>(AO, Wo, bo, (float*)d_out);
}

// Round 9
// 259.978 us; speedup vs baseline: 1.0575x; 1.0575x over previous
//
#include <hip/hip_runtime.h>
#include <hip/hip_bf16.h>

// Problem constants: B=2, L=2048, D=1024, H=16, d_k=64
#define Hh 16
#define Ll 2048
#define Dd 1024
#define DK 64
#define Mm 4096  // B*L
#define Kk 1024
#define Nn 1024

typedef short bf16x8 __attribute__((ext_vector_type(8)));
typedef float f32x4 __attribute__((ext_vector_type(4)));

static __device__ __forceinline__ unsigned short f2bf(float f) {
    union { __hip_bfloat16 b; unsigned short u; } cv;
    cv.b = __float2bfloat16(f);
    return cv.u;
}

// truncate-pack two fp32 -> bf16x2 (a in low half). Single v_perm_b32.
static __device__ __forceinline__ unsigned packtr(float a, float b) {
    return __builtin_amdgcn_perm(__builtin_bit_cast(unsigned, b),
                                 __builtin_bit_cast(unsigned, a), 0x07060302u);
}

static __device__ __forceinline__ float fexp2(float x) {
    return __builtin_amdgcn_exp2f(x);  // single v_exp_f32
}

// async global->LDS, 16B/lane. LDS dest = wave-uniform base + lane*16 (HW rule).
static __device__ __forceinline__ void glds16(const ushort* g, ushort* l) {
    __builtin_amdgcn_global_load_lds((const __attribute__((address_space(1))) unsigned int*)g,
                                     (__attribute__((address_space(3))) unsigned int*)l,
                                     16, 0, 0);
}

// ---------------- fused fp32 -> bf16 casts ----------------
__global__ __launch_bounds__(256) void cast_all(
    const float* __restrict__ q, const float* __restrict__ k, const float* __restrict__ v,
    const float* __restrict__ wq, const float* __restrict__ wk, const float* __restrict__ wv,
    const float* __restrict__ wo,
    ushort* __restrict__ qb, ushort* __restrict__ kb, ushort* __restrict__ vb,
    ushort* __restrict__ wqb, ushort* __restrict__ wkb, ushort* __restrict__ wvb,
    ushort* __restrict__ wob) {
    const int bx = blockIdx.x;
    const float4* s; ushort4* d; int base;
    if      (bx <  4096) { s = (const float4*)q;  d = (ushort4*)qb;  base = 0; }
    else if (bx <  8192) { s = (const float4*)k;  d = (ushort4*)kb;  base = 4096; }
    else if (bx < 12288) { s = (const float4*)v;  d = (ushort4*)vb;  base = 8192; }
    else if (bx < 13312) { s = (const float4*)wq; d = (ushort4*)wqb; base = 12288; }
    else if (bx < 14336) { s = (const float4*)wk; d = (ushort4*)wkb; base = 13312; }
    else if (bx < 15360) { s = (const float4*)wv; d = (ushort4*)wvb; base = 14336; }
    else                 { s = (const float4*)wo; d = (ushort4*)wob; base = 15360; }
    const int i = (bx - base) * 256 + threadIdx.x;
    float4 vv = s[i];
    ushort4 o;
    o.x = f2bf(vv.x); o.y = f2bf(vv.y); o.z = f2bf(vv.z); o.w = f2bf(vv.w);
    d[i] = o;
}

// ---------------- fused QKV projection GEMM (bf16, BK=32) ----------------
// C = A @ W^T + bias. z=0: Q, pre-scaled by 0.125*log2(e), -> [BH,L,64].
// z=1: K -> [BH,L,64]. z=2: V, LDS-transposed epilogue -> [BH,64,L].
__global__ __launch_bounds__(256) void gemm_qkv(
    const ushort* __restrict__ A0, const ushort* __restrict__ A1, const ushort* __restrict__ A2,
    const ushort* __restrict__ W0, const ushort* __restrict__ W1, const ushort* __restrict__ W2,
    const float* __restrict__ b0, const float* __restrict__ b1, const float* __restrict__ b2,
    ushort* __restrict__ O0, ushort* __restrict__ O1, ushort* __restrict__ OVt) {
    __shared__ __align__(16) ushort SM[2 * 128 * 32];  // As | Bs ; reused in epilogues
    ushort* As = SM;
    ushort* Bs = SM + 4096;
    const int z = blockIdx.z;
    const ushort* A = (z == 0) ? A0 : (z == 1) ? A1 : A2;
    const ushort* W = (z == 0) ? W0 : (z == 1) ? W1 : W2;
    const float* bias = (z == 0) ? b0 : (z == 1) ? b1 : b2;

    const int t = threadIdx.x;
    const int wave = t >> 6, lane = t & 63;
    const int quad = lane >> 4, l15 = lane & 15;
    const int brow = blockIdx.y * 128, bcol = blockIdx.x * 128;
    const int wr = (wave >> 1) * 64, wc = (wave & 1) * 64;
    const int gr = wave * 16 + (lane >> 2);
    const int gc = (lane & 3) * 8;

    f32x4 acc[4][4] = {};

    for (int k0 = 0; k0 < Kk; k0 += 32) {
        __syncthreads();
        glds16(A + (size_t)(brow + gr) * Kk + k0 + gc,      As + wave * 512);
        glds16(A + (size_t)(brow + 64 + gr) * Kk + k0 + gc, As + 2048 + wave * 512);
        glds16(W + (size_t)(bcol + gr) * Kk + k0 + gc,      Bs + wave * 512);
        glds16(W + (size_t)(bcol + 64 + gr) * Kk + k0 + gc, Bs + 2048 + wave * 512);
        __syncthreads();

        bf16x8 af[4], bfr[4];
#pragma unroll
        for (int i = 0; i < 4; i++)
            af[i] = *(const bf16x8*)(As + (wr + i * 16 + l15) * 32 + quad * 8);
#pragma unroll
        for (int j = 0; j < 4; j++)
            bfr[j] = *(const bf16x8*)(Bs + (wc + j * 16 + l15) * 32 + quad * 8);
#pragma unroll
        for (int i = 0; i < 4; i++)
#pragma unroll
            for (int j = 0; j < 4; j++)
                acc[i][j] = __builtin_amdgcn_mfma_f32_16x16x32_bf16(af[i], bfr[j], acc[i][j], 0, 0, 0);
    }

    // C/D layout: row = quad*4+r, col = l15
    if (z < 2) {
        // Repack each wave's 64x64 tile (one head) through LDS -> coalesced 16B stores.
        ushort* Out = (z == 0) ? O0 : O1;
        const float oscl = (z == 0) ? 0.18033688f : 1.0f;  // 0.125*log2(e) folded into Q
        const int b = brow >> 11;
        const int lbase = (brow & 2047) + wr;
        const int h = (bcol + wc) >> 6;           // one head per wave
        ushort* T = SM + wave * 1280;             // [16][80] per wave (odd dword stride)
        __syncthreads();                          // staging reads done; safe to reuse SM
#pragma unroll
        for (int i = 0; i < 4; i++) {
#pragma unroll
            for (int j = 0; j < 4; j++) {
                const float bv = bias[bcol + wc + j * 16 + l15];
#pragma unroll
                for (int r = 0; r < 4; r++)
                    T[(quad * 4 + r) * 80 + j * 16 + l15] = f2bf((acc[i][j][r] + bv) * oscl);
            }
            const int r8 = lane >> 3, c8 = lane & 7;
#pragma unroll
            for (int pass = 0; pass < 2; pass++) {
                const uint4 val = *(const uint4*)(T + (pass * 8 + r8) * 80 + c8 * 8);
                const int l = lbase + i * 16 + pass * 8 + r8;
                *(uint4*)(Out + ((size_t)(b * Hh + h) * Ll + l) * DK + c8 * 8) = val;
            }
        }
    } else {
        // LDS transpose epilogue: emit V^T [BH, 64, L] with coalesced 16B stores.
        ushort* T = SM;  // T[32][136]
        const int b = brow >> 11;
        const int lbase = brow & 2047;
        const int npr = (wave & 1) * 16 + l15;
#pragma unroll
        for (int j = 0; j < 4; j++) {
            __syncthreads();
            const float bv = bias[bcol + wc + j * 16 + l15];
#pragma unroll
            for (int i = 0; i < 4; i++)
#pragma unroll
                for (int r = 0; r < 4; r++) {
                    const int m = wr + i * 16 + quad * 4 + r;
                    T[npr * 136 + m] = f2bf(acc[i][j][r] + bv);
                }
            __syncthreads();
#pragma unroll
            for (int cc = 0; cc < 2; cc++) {
                const int idx = t + cc * 256;
                const int ni = idx >> 4;
                const int ms = idx & 15;
                const int n = bcol + (ni >> 4) * 64 + j * 16 + (ni & 15);
                const int hh = n >> 6, dk = n & 63;
                uint4 val = *(const uint4*)(T + ni * 136 + ms * 8);
                *(uint4*)(OVt + ((size_t)(b * Hh + hh) * DK + dk) * Ll + lbase + ms * 8) = val;
            }
        }
    }
}

// ---------------- fused attention (R6 version, unchanged) ----------------
__global__ __launch_bounds__(256) void attn_kernel(const ushort* __restrict__ Q,
                                                   const ushort* __restrict__ Kp,
                                                   const ushort* __restrict__ Vt,
                                                   ushort* __restrict__ Oout,
                                                   const int* __restrict__ masksize) {
    __shared__ __align__(16) ushort Ks[2 * 128 * 32];  // 16KB
    __shared__ __align__(16) ushort Vs[64 * 128];      // 16KB
    const int t = threadIdx.x;
    const int wave = t >> 6, lane = t & 63;
    const int quad = lane >> 4, l15 = lane & 15;
    const int bx = blockIdx.x;
    const int bh = bx & 31, qc = bx >> 5;
    const int q0w = qc * 128 + wave * 32;
    const int half = masksize[0] >> 1;
    const unsigned wid = (unsigned)(2 * half);

    const ushort* Qb = Q + (size_t)bh * (Ll * DK);
    const ushort* Kb = Kp + (size_t)bh * (Ll * DK);
    const ushort* Vb = Vt + (size_t)bh * (DK * Ll);

    const bf16x8 qA0 = *(const bf16x8*)(Qb + (size_t)(q0w + l15) * DK + quad * 8);
    const bf16x8 qA1 = *(const bf16x8*)(Qb + (size_t)(q0w + l15) * DK + 32 + quad * 8);
    const bf16x8 qB0 = *(const bf16x8*)(Qb + (size_t)(q0w + 16 + l15) * DK + quad * 8);
    const bf16x8 qB1 = *(const bf16x8*)(Qb + (size_t)(q0w + 16 + l15) * DK + 32 + quad * 8);

    const float C2IN  = (1.0f - 24.0f) * 1.44269504088896f;
    const float C2OUT = -24.0f * 1.44269504088896f;
    const float E1 = 2.718281828f;

    bf16x8 onesf;
#pragma unroll
    for (int j = 0; j < 8; j++) onesf[j] = (short)0x3F80;

    f32x4 OA[4] = {}, OB[4] = {};
    f32x4 SA = {}, SB = {};

    const int krow = lane >> 2;
    const int kcol8 = (lane & 3) * 8;
    const int vdl = lane >> 4;
    const int vg0 = 2 * (lane & 15);

    for (int kt = 0; kt < Ll; kt += 128) {
        __syncthreads();
        if (wave < 2) {
            const int cbase = wave * 4;
#pragma unroll
            for (int c = 0; c < 4; c++)
#pragma unroll
                for (int pan = 0; pan < 2; pan++)
                    glds16(Kb + (size_t)(kt + (cbase + c) * 16 + krow) * DK + pan * 32 + kcol8,
                           Ks + (pan * 128 + (cbase + c) * 16) * 32);
        } else {
            const int sb = (wave - 2) * 8;
#pragma unroll
            for (int i = 0; i < 8; i++) {
                const int sidx = sb + i;
                const int d = sidx * 4 + vdl;
                const int g0 = vg0 ^ (d & 30);
                glds16(Vb + (size_t)d * Ll + kt + g0 * 4, Vs + sidx * 512);
            }
        }
        __syncthreads();

        const int qlo = q0w, qhi = q0w + 31;
        const bool allout = (kt + 127 < qlo - half) || (kt > qhi + half);
        const bool allin  = (kt >= qhi - half) && (kt + 127 <= qlo + half);
        const bool uniform = allin || allout;
        const float cinit = allin ? C2IN : C2OUT;
        f32x4 cvec = {cinit, cinit, cinit, cinit};

#pragma unroll
        for (int s = 0; s < 4; s++) {
            const bf16x8 kf00 = *(const bf16x8*)(Ks + ((2 * s) * 16 + l15) * 32 + quad * 8);
            const bf16x8 kf01 = *(const bf16x8*)(Ks + 4096 + ((2 * s) * 16 + l15) * 32 + quad * 8);
            const bf16x8 kf10 = *(const bf16x8*)(Ks + ((2 * s + 1) * 16 + l15) * 32 + quad * 8);
            const bf16x8 kf11 = *(const bf16x8*)(Ks + 4096 + ((2 * s + 1) * 16 + l15) * 32 + quad * 8);
            f32x4 zA0 = __builtin_amdgcn_mfma_f32_16x16x32_bf16(kf00, qA0, cvec, 0, 0, 0);
            zA0 = __builtin_amdgcn_mfma_f32_16x16x32_bf16(kf01, qA1, zA0, 0, 0, 0);
            f32x4 zA1 = __builtin_amdgcn_mfma_f32_16x16x32_bf16(kf10, qA0, cvec, 0, 0, 0);
            zA1 = __builtin_amdgcn_mfma_f32_16x16x32_bf16(kf11, qA1, zA1, 0, 0, 0);
            f32x4 zB0 = __builtin_amdgcn_mfma_f32_16x16x32_bf16(kf00, qB0, cvec, 0, 0, 0);
            zB0 = __builtin_amdgcn_mfma_f32_16x16x32_bf16(kf01, qB1, zB0, 0, 0, 0);
            f32x4 zB1 = __builtin_amdgcn_mfma_f32_16x16x32_bf16(kf10, qB0, cvec, 0, 0, 0);
            zB1 = __builtin_amdgcn_mfma_f32_16x16x32_bf16(kf11, qB1, zB1, 0, 0, 0);

            float pA[8], pB[8];
            if (uniform) {
#pragma unroll
                for (int g = 0; g < 2; g++)
#pragma unroll
                    for (int r = 0; r < 4; r++) {
                        pA[g * 4 + r] = fexp2(g ? zA1[r] : zA0[r]);
                        pB[g * 4 + r] = fexp2(g ? zB1[r] : zB0[r]);
                    }
            } else {
                const int kb = kt + s * 32 + quad * 4 + half;
#pragma unroll
                for (int g = 0; g < 2; g++)
#pragma unroll
                    for (int r = 0; r < 4; r++) {
                        const unsigned ttA = (unsigned)(kb + g * 16 + r - (q0w + l15));
                        const unsigned ttB = (unsigned)(kb + g * 16 + r - (q0w + 16 + l15));
                        pA[g * 4 + r] = fexp2(g ? zA1[r] : zA0[r]) * (ttA <= wid ? E1 : 1.0f);
                        pB[g * 4 + r] = fexp2(g ? zB1[r] : zB0[r]) * (ttB <= wid ? E1 : 1.0f);
                    }
            }

            bf16x8 pfA, pfB;
            ((unsigned*)&pfA)[0] = packtr(pA[0], pA[1]);
            ((unsigned*)&pfA)[1] = packtr(pA[2], pA[3]);
            ((unsigned*)&pfA)[2] = packtr(pA[4], pA[5]);
            ((unsigned*)&pfA)[3] = packtr(pA[6], pA[7]);
            ((unsigned*)&pfB)[0] = packtr(pB[0], pB[1]);
            ((unsigned*)&pfB)[1] = packtr(pB[2], pB[3]);
            ((unsigned*)&pfB)[2] = packtr(pB[4], pB[5]);
            ((unsigned*)&pfB)[3] = packtr(pB[6], pB[7]);

            SA = __builtin_amdgcn_mfma_f32_16x16x32_bf16(pfA, onesf, SA, 0, 0, 0);
            SB = __builtin_amdgcn_mfma_f32_16x16x32_bf16(pfB, onesf, SB, 0, 0, 0);

#pragma unroll
            for (int i = 0; i < 4; i++) {
                const int d = i * 16 + l15;
                const int x4 = (d & 30) * 4;
                const int bi = d * 128;
                const ushort4 v1 = *(const ushort4*)(Vs + bi + (((s * 8 + quad) * 4) ^ x4));
                const ushort4 v2 = *(const ushort4*)(Vs + bi + (((s * 8 + 4 + quad) * 4) ^ x4));
                bf16x8 vc;
                *(ushort4*)&vc = v1;
                *((ushort4*)&vc + 1) = v2;
                OA[i] = __builtin_amdgcn_mfma_f32_16x16x32_bf16(pfA, vc, OA[i], 0, 0, 0);
                OB[i] = __builtin_amdgcn_mfma_f32_16x16x32_bf16(pfB, vc, OB[i], 0, 0, 0);
            }
        }
    }

    float liA[4], liB[4];
#pragma unroll
    for (int r = 0; r < 4; r++) {
        liA[r] = 1.0f / SA[r];
        liB[r] = 1.0f / SB[r];
    }

    const int b = bh >> 4, h = bh & 15;
#pragma unroll
    for (int i = 0; i < 4; i++)
#pragma unroll
        for (int r = 0; r < 4; r++) {
            const int qa = q0w + quad * 4 + r;
            Oout[((size_t)b * Ll + qa) * Dd + h * DK + i * 16 + l15] = f2bf(OA[i][r] * liA[r]);
            Oout[((size_t)b * Ll + qa + 16) * Dd + h * DK + i * 16 + l15] = f2bf(OB[i][r] * liB[r]);
        }
}

// ---------------- output projection GEMM: split-K=2, 128x128, atomic epilogue ----------------
// Out must be pre-zeroed (hipMemsetAsync). Slice z does K [z*512, z*512+512);
// bias added by slice 0. Grid (8,32,2) = 512 blocks = 2/CU, 16 K-iters/block.
__global__ __launch_bounds__(256) void gemm_o(const ushort* __restrict__ A,
                                              const ushort* __restrict__ W,
                                              const float* __restrict__ bias,
                                              float* __restrict__ Out) {
    __shared__ __align__(16) ushort As[128 * 32];
    __shared__ __align__(16) ushort Bs[128 * 32];
    const int t = threadIdx.x;
    const int wave = t >> 6, lane = t & 63;
    const int quad = lane >> 4, l15 = lane & 15;
    const int brow = blockIdx.y * 128, bcol = blockIdx.x * 128;
    const int ks = blockIdx.z * 512;
    const int wr = (wave >> 1) * 64, wc = (wave & 1) * 64;
    const int gr = wave * 16 + (lane >> 2);
    const int gc = (lane & 3) * 8;

    f32x4 acc[4][4] = {};

    for (int k0 = ks; k0 < ks + 512; k0 += 32) {
        __syncthreads();
        glds16(A + (size_t)(brow + gr) * Kk + k0 + gc,      As + wave * 512);
        glds16(A + (size_t)(brow + 64 + gr) * Kk + k0 + gc, As + 2048 + wave * 512);
        glds16(W + (size_t)(bcol + gr) * Kk + k0 + gc,      Bs + wave * 512);
        glds16(W + (size_t)(bcol + 64 + gr) * Kk + k0 + gc, Bs + 2048 + wave * 512);
        __syncthreads();

        bf16x8 af[4], bfr[4];
#pragma unroll
        for (int i = 0; i < 4; i++)
            af[i] = *(const bf16x8*)(As + (wr + i * 16 + l15) * 32 + quad * 8);
#pragma unroll
        for (int j = 0; j < 4; j++)
            bfr[j] = *(const bf16x8*)(Bs + (wc + j * 16 + l15) * 32 + quad * 8);
#pragma unroll
        for (int i = 0; i < 4; i++)
#pragma unroll
            for (int j = 0; j < 4; j++)
                acc[i][j] = __builtin_amdgcn_mfma_f32_16x16x32_bf16(af[i], bfr[j], acc[i][j], 0, 0, 0);
    }

    const bool addb = (blockIdx.z == 0);
#pragma unroll
    for (int i = 0; i < 4; i++)
#pragma unroll
        for (int j = 0; j < 4; j++) {
            const int n = bcol + wc + j * 16 + l15;
            const float bv = addb ? bias[n] : 0.0f;
#pragma unroll
            for (int r = 0; r < 4; r++) {
                const int m = brow + wr + i * 16 + quad * 4 + r;
                atomicAdd(&Out[(size_t)m * Nn + n], acc[i][j][r] + bv);
            }
        }
}

// ---------------- launch ----------------
extern "C" void kernel_launch(void* const* d_in, const int* in_sizes, int n_in,
                              void* d_out, int out_size, void* d_ws, size_t ws_size,
                              hipStream_t stream) {
    const float* query = (const float*)d_in[0];
    const float* key   = (const float*)d_in[1];
    const float* value = (const float*)d_in[2];
    const float* Wq = (const float*)d_in[3];
    const float* bq = (const float*)d_in[4];
    const float* Wk = (const float*)d_in[5];
    const float* bk = (const float*)d_in[6];
    const float* Wv = (const float*)d_in[7];
    const float* bv = (const float*)d_in[8];
    const float* Wo = (const float*)d_in[9];
    const float* bo = (const float*)d_in[10];
    const int* masksize = (const int*)d_in[11];

    char* ws = (char*)d_ws;
    const size_t MB = 1024 * 1024;
    ushort* qb  = (ushort*)(ws + 0 * MB);
    ushort* kbf = (ushort*)(ws + 8 * MB);
    ushort* vbf = (ushort*)(ws + 16 * MB);
    ushort* wqb = (ushort*)(ws + 24 * MB);
    ushort* wkb = (ushort*)(ws + 26 * MB);
    ushort* wvb = (ushort*)(ws + 28 * MB);
    ushort* wob = (ushort*)(ws + 30 * MB);
    ushort* Qp  = (ushort*)(ws + 32 * MB);  // [BH, L, 64], pre-scaled by 0.125*log2e
    ushort* Kp  = (ushort*)(ws + 40 * MB);  // [BH, L, 64]
    ushort* Vt  = (ushort*)(ws + 48 * MB);  // [BH, 64, L]
    ushort* AO  = (ushort*)(ws + 56 * MB);  // [4096, 1024]

    // zero d_out for the split-K atomic epilogue (stream op: graph-capturable)
    hipMemsetAsync(d_out, 0, (size_t)Mm * Nn * sizeof(float), stream);

    cast_all<<<16384, 256, 0, stream>>>(query, key, value, Wq, Wk, Wv, Wo,
                                        qb, kbf, vbf, wqb, wkb, wvb, wob);

    gemm_qkv<<<dim3(8, 32, 3), 256, 0, stream>>>(qb, kbf, vbf,
                                                 wqb, wkb, wvb,
                                                 bq, bk, bv,
                                                 Qp, Kp, Vt);

    attn_kernel<<<512, 256, 0, stream>>>(Qp, Kp, Vt, AO, masksize);

    gemm_o<<<dim3(8, 32, 2), 256, 0, stream>>>(AO, wob, bo, (float*)d_out);
}

// Round 10
// 217.929 us; speedup vs baseline: 1.2615x; 1.1930x over previous
//
#include <hip/hip_runtime.h>
#include <hip/hip_bf16.h>

// Problem constants: B=2, L=2048, D=1024, H=16, d_k=64
#define Hh 16
#define Ll 2048
#define Dd 1024
#define DK 64
#define Mm 4096  // B*L
#define Kk 1024
#define Nn 1024

typedef short bf16x8 __attribute__((ext_vector_type(8)));
typedef float f32x4 __attribute__((ext_vector_type(4)));

static __device__ __forceinline__ unsigned short f2bf(float f) {
    union { __hip_bfloat16 b; unsigned short u; } cv;
    cv.b = __float2bfloat16(f);
    return cv.u;
}

// truncate-pack two fp32 -> bf16x2 (a in low half). Single v_perm_b32.
static __device__ __forceinline__ unsigned packtr(float a, float b) {
    return __builtin_amdgcn_perm(__builtin_bit_cast(unsigned, b),
                                 __builtin_bit_cast(unsigned, a), 0x07060302u);
}

static __device__ __forceinline__ float fexp2(float x) {
    return __builtin_amdgcn_exp2f(x);  // single v_exp_f32
}

// async global->LDS, 16B/lane. LDS dest = wave-uniform base + lane*16 (HW rule).
static __device__ __forceinline__ void glds16(const ushort* g, ushort* l) {
    __builtin_amdgcn_global_load_lds((const __attribute__((address_space(1))) unsigned int*)g,
                                     (__attribute__((address_space(3))) unsigned int*)l,
                                     16, 0, 0);
}

// ---------------- fused fp32 -> bf16 casts ----------------
__global__ __launch_bounds__(256) void cast_all(
    const float* __restrict__ q, const float* __restrict__ k, const float* __restrict__ v,
    const float* __restrict__ wq, const float* __restrict__ wk, const float* __restrict__ wv,
    const float* __restrict__ wo,
    ushort* __restrict__ qb, ushort* __restrict__ kb, ushort* __restrict__ vb,
    ushort* __restrict__ wqb, ushort* __restrict__ wkb, ushort* __restrict__ wvb,
    ushort* __restrict__ wob) {
    const int bx = blockIdx.x;
    const float4* s; ushort4* d; int base;
    if      (bx <  4096) { s = (const float4*)q;  d = (ushort4*)qb;  base = 0; }
    else if (bx <  8192) { s = (const float4*)k;  d = (ushort4*)kb;  base = 4096; }
    else if (bx < 12288) { s = (const float4*)v;  d = (ushort4*)vb;  base = 8192; }
    else if (bx < 13312) { s = (const float4*)wq; d = (ushort4*)wqb; base = 12288; }
    else if (bx < 14336) { s = (const float4*)wk; d = (ushort4*)wkb; base = 13312; }
    else if (bx < 15360) { s = (const float4*)wv; d = (ushort4*)wvb; base = 14336; }
    else                 { s = (const float4*)wo; d = (ushort4*)wob; base = 15360; }
    const int i = (bx - base) * 256 + threadIdx.x;
    float4 vv = s[i];
    ushort4 o;
    o.x = f2bf(vv.x); o.y = f2bf(vv.y); o.z = f2bf(vv.z); o.w = f2bf(vv.w);
    d[i] = o;
}

// ---------------- fused QKV projection GEMM (bf16, BK=32, XCD-affine) ----------------
// 1D grid 768; flat = xcd + 8*bcol + 64*slot, group g = slot*8 + xcd.
// All 8 bcol-blocks of a group (same brow,z A-panel) share one XCD's L2.
// z=0: Q (pre-scaled 0.125*log2e) -> [BH,L,64]; z=1: K; z=2: V^T -> [BH,64,L].
__global__ __launch_bounds__(256) void gemm_qkv(
    const ushort* __restrict__ A0, const ushort* __restrict__ A1, const ushort* __restrict__ A2,
    const ushort* __restrict__ W0, const ushort* __restrict__ W1, const ushort* __restrict__ W2,
    const float* __restrict__ b0, const float* __restrict__ b1, const float* __restrict__ b2,
    ushort* __restrict__ O0, ushort* __restrict__ O1, ushort* __restrict__ OVt) {
    __shared__ __align__(16) ushort SM[2 * 128 * 32];  // As | Bs ; reused in epilogues
    ushort* As = SM;
    ushort* Bs = SM + 4096;

    const int fl = blockIdx.x;
    const int xcd = fl & 7, bcoli = (fl >> 3) & 7, slot = fl >> 6;
    const int g = slot * 8 + xcd;        // 0..95
    const int z = g >> 5;                // 0..2
    const int browi = g & 31;            // 0..31

    const ushort* A = (z == 0) ? A0 : (z == 1) ? A1 : A2;
    const ushort* W = (z == 0) ? W0 : (z == 1) ? W1 : W2;
    const float* bias = (z == 0) ? b0 : (z == 1) ? b1 : b2;

    const int t = threadIdx.x;
    const int wave = t >> 6, lane = t & 63;
    const int quad = lane >> 4, l15 = lane & 15;
    const int brow = browi * 128, bcol = bcoli * 128;
    const int wr = (wave >> 1) * 64, wc = (wave & 1) * 64;
    const int gr = wave * 16 + (lane >> 2);
    const int gc = (lane & 3) * 8;

    f32x4 acc[4][4] = {};

    for (int k0 = 0; k0 < Kk; k0 += 32) {
        __syncthreads();
        glds16(A + (size_t)(brow + gr) * Kk + k0 + gc,      As + wave * 512);
        glds16(A + (size_t)(brow + 64 + gr) * Kk + k0 + gc, As + 2048 + wave * 512);
        glds16(W + (size_t)(bcol + gr) * Kk + k0 + gc,      Bs + wave * 512);
        glds16(W + (size_t)(bcol + 64 + gr) * Kk + k0 + gc, Bs + 2048 + wave * 512);
        __syncthreads();

        bf16x8 af[4], bfr[4];
#pragma unroll
        for (int i = 0; i < 4; i++)
            af[i] = *(const bf16x8*)(As + (wr + i * 16 + l15) * 32 + quad * 8);
#pragma unroll
        for (int j = 0; j < 4; j++)
            bfr[j] = *(const bf16x8*)(Bs + (wc + j * 16 + l15) * 32 + quad * 8);
#pragma unroll
        for (int i = 0; i < 4; i++)
#pragma unroll
            for (int j = 0; j < 4; j++)
                acc[i][j] = __builtin_amdgcn_mfma_f32_16x16x32_bf16(af[i], bfr[j], acc[i][j], 0, 0, 0);
    }

    // C/D layout: row = quad*4+r, col = l15
    if (z < 2) {
        // Repack each wave's 64x64 tile (one head) through LDS -> coalesced 16B stores.
        ushort* Out = (z == 0) ? O0 : O1;
        const float oscl = (z == 0) ? 0.18033688f : 1.0f;  // 0.125*log2(e) folded into Q
        const int b = brow >> 11;
        const int lbase = (brow & 2047) + wr;
        const int h = (bcol + wc) >> 6;           // one head per wave
        ushort* T = SM + wave * 1280;             // [16][80] per wave (odd dword stride)
        __syncthreads();                          // staging reads done; safe to reuse SM
#pragma unroll
        for (int i = 0; i < 4; i++) {
#pragma unroll
            for (int j = 0; j < 4; j++) {
                const float bv = bias[bcol + wc + j * 16 + l15];
#pragma unroll
                for (int r = 0; r < 4; r++)
                    T[(quad * 4 + r) * 80 + j * 16 + l15] = f2bf((acc[i][j][r] + bv) * oscl);
            }
            const int r8 = lane >> 3, c8 = lane & 7;
#pragma unroll
            for (int pass = 0; pass < 2; pass++) {
                const uint4 val = *(const uint4*)(T + (pass * 8 + r8) * 80 + c8 * 8);
                const int l = lbase + i * 16 + pass * 8 + r8;
                *(uint4*)(Out + ((size_t)(b * Hh + h) * Ll + l) * DK + c8 * 8) = val;
            }
        }
    } else {
        // LDS transpose epilogue: emit V^T [BH, 64, L] with coalesced 16B stores.
        ushort* T = SM;  // T[32][136]
        const int b = brow >> 11;
        const int lbase = brow & 2047;
        const int npr = (wave & 1) * 16 + l15;
#pragma unroll
        for (int j = 0; j < 4; j++) {
            __syncthreads();
            const float bv = bias[bcol + wc + j * 16 + l15];
#pragma unroll
            for (int i = 0; i < 4; i++)
#pragma unroll
                for (int r = 0; r < 4; r++) {
                    const int m = wr + i * 16 + quad * 4 + r;
                    T[npr * 136 + m] = f2bf(acc[i][j][r] + bv);
                }
            __syncthreads();
#pragma unroll
            for (int cc = 0; cc < 2; cc++) {
                const int idx = t + cc * 256;
                const int ni = idx >> 4;
                const int ms = idx & 15;
                const int n = bcol + (ni >> 4) * 64 + j * 16 + (ni & 15);
                const int hh = n >> 6, dk = n & 63;
                uint4 val = *(const uint4*)(T + ni * 136 + ms * 8);
                *(uint4*)(OVt + ((size_t)(b * Hh + hh) * DK + dk) * Ll + lbase + ms * 8) = val;
            }
        }
    }
}

// ---------------- fused attention (R6 version, unchanged) ----------------
__global__ __launch_bounds__(256) void attn_kernel(const ushort* __restrict__ Q,
                                                   const ushort* __restrict__ Kp,
                                                   const ushort* __restrict__ Vt,
                                                   ushort* __restrict__ Oout,
                                                   const int* __restrict__ masksize) {
    __shared__ __align__(16) ushort Ks[2 * 128 * 32];  // 16KB
    __shared__ __align__(16) ushort Vs[64 * 128];      // 16KB
    const int t = threadIdx.x;
    const int wave = t >> 6, lane = t & 63;
    const int quad = lane >> 4, l15 = lane & 15;
    const int bx = blockIdx.x;
    const int bh = bx & 31, qc = bx >> 5;
    const int q0w = qc * 128 + wave * 32;
    const int half = masksize[0] >> 1;
    const unsigned wid = (unsigned)(2 * half);

    const ushort* Qb = Q + (size_t)bh * (Ll * DK);
    const ushort* Kb = Kp + (size_t)bh * (Ll * DK);
    const ushort* Vb = Vt + (size_t)bh * (DK * Ll);

    const bf16x8 qA0 = *(const bf16x8*)(Qb + (size_t)(q0w + l15) * DK + quad * 8);
    const bf16x8 qA1 = *(const bf16x8*)(Qb + (size_t)(q0w + l15) * DK + 32 + quad * 8);
    const bf16x8 qB0 = *(const bf16x8*)(Qb + (size_t)(q0w + 16 + l15) * DK + quad * 8);
    const bf16x8 qB1 = *(const bf16x8*)(Qb + (size_t)(q0w + 16 + l15) * DK + 32 + quad * 8);

    const float C2IN  = (1.0f - 24.0f) * 1.44269504088896f;
    const float C2OUT = -24.0f * 1.44269504088896f;
    const float E1 = 2.718281828f;

    bf16x8 onesf;
#pragma unroll
    for (int j = 0; j < 8; j++) onesf[j] = (short)0x3F80;

    f32x4 OA[4] = {}, OB[4] = {};
    f32x4 SA = {}, SB = {};

    const int krow = lane >> 2;
    const int kcol8 = (lane & 3) * 8;
    const int vdl = lane >> 4;
    const int vg0 = 2 * (lane & 15);

    for (int kt = 0; kt < Ll; kt += 128) {
        __syncthreads();
        if (wave < 2) {
            const int cbase = wave * 4;
#pragma unroll
            for (int c = 0; c < 4; c++)
#pragma unroll
                for (int pan = 0; pan < 2; pan++)
                    glds16(Kb + (size_t)(kt + (cbase + c) * 16 + krow) * DK + pan * 32 + kcol8,
                           Ks + (pan * 128 + (cbase + c) * 16) * 32);
        } else {
            const int sb = (wave - 2) * 8;
#pragma unroll
            for (int i = 0; i < 8; i++) {
                const int sidx = sb + i;
                const int d = sidx * 4 + vdl;
                const int g0 = vg0 ^ (d & 30);
                glds16(Vb + (size_t)d * Ll + kt + g0 * 4, Vs + sidx * 512);
            }
        }
        __syncthreads();

        const int qlo = q0w, qhi = q0w + 31;
        const bool allout = (kt + 127 < qlo - half) || (kt > qhi + half);
        const bool allin  = (kt >= qhi - half) && (kt + 127 <= qlo + half);
        const bool uniform = allin || allout;
        const float cinit = allin ? C2IN : C2OUT;
        f32x4 cvec = {cinit, cinit, cinit, cinit};

#pragma unroll
        for (int s = 0; s < 4; s++) {
            const bf16x8 kf00 = *(const bf16x8*)(Ks + ((2 * s) * 16 + l15) * 32 + quad * 8);
            const bf16x8 kf01 = *(const bf16x8*)(Ks + 4096 + ((2 * s) * 16 + l15) * 32 + quad * 8);
            const bf16x8 kf10 = *(const bf16x8*)(Ks + ((2 * s + 1) * 16 + l15) * 32 + quad * 8);
            const bf16x8 kf11 = *(const bf16x8*)(Ks + 4096 + ((2 * s + 1) * 16 + l15) * 32 + quad * 8);
            f32x4 zA0 = __builtin_amdgcn_mfma_f32_16x16x32_bf16(kf00, qA0, cvec, 0, 0, 0);
            zA0 = __builtin_amdgcn_mfma_f32_16x16x32_bf16(kf01, qA1, zA0, 0, 0, 0);
            f32x4 zA1 = __builtin_amdgcn_mfma_f32_16x16x32_bf16(kf10, qA0, cvec, 0, 0, 0);
            zA1 = __builtin_amdgcn_mfma_f32_16x16x32_bf16(kf11, qA1, zA1, 0, 0, 0);
            f32x4 zB0 = __builtin_amdgcn_mfma_f32_16x16x32_bf16(kf00, qB0, cvec, 0, 0, 0);
            zB0 = __builtin_amdgcn_mfma_f32_16x16x32_bf16(kf01, qB1, zB0, 0, 0, 0);
            f32x4 zB1 = __builtin_amdgcn_mfma_f32_16x16x32_bf16(kf10, qB0, cvec, 0, 0, 0);
            zB1 = __builtin_amdgcn_mfma_f32_16x16x32_bf16(kf11, qB1, zB1, 0, 0, 0);

            float pA[8], pB[8];
            if (uniform) {
#pragma unroll
                for (int g = 0; g < 2; g++)
#pragma unroll
                    for (int r = 0; r < 4; r++) {
                        pA[g * 4 + r] = fexp2(g ? zA1[r] : zA0[r]);
                        pB[g * 4 + r] = fexp2(g ? zB1[r] : zB0[r]);
                    }
            } else {
                const int kb = kt + s * 32 + quad * 4 + half;
#pragma unroll
                for (int g = 0; g < 2; g++)
#pragma unroll
                    for (int r = 0; r < 4; r++) {
                        const unsigned ttA = (unsigned)(kb + g * 16 + r - (q0w + l15));
                        const unsigned ttB = (unsigned)(kb + g * 16 + r - (q0w + 16 + l15));
                        pA[g * 4 + r] = fexp2(g ? zA1[r] : zA0[r]) * (ttA <= wid ? E1 : 1.0f);
                        pB[g * 4 + r] = fexp2(g ? zB1[r] : zB0[r]) * (ttB <= wid ? E1 : 1.0f);
                    }
            }

            bf16x8 pfA, pfB;
            ((unsigned*)&pfA)[0] = packtr(pA[0], pA[1]);
            ((unsigned*)&pfA)[1] = packtr(pA[2], pA[3]);
            ((unsigned*)&pfA)[2] = packtr(pA[4], pA[5]);
            ((unsigned*)&pfA)[3] = packtr(pA[6], pA[7]);
            ((unsigned*)&pfB)[0] = packtr(pB[0], pB[1]);
            ((unsigned*)&pfB)[1] = packtr(pB[2], pB[3]);
            ((unsigned*)&pfB)[2] = packtr(pB[4], pB[5]);
            ((unsigned*)&pfB)[3] = packtr(pB[6], pB[7]);

            SA = __builtin_amdgcn_mfma_f32_16x16x32_bf16(pfA, onesf, SA, 0, 0, 0);
            SB = __builtin_amdgcn_mfma_f32_16x16x32_bf16(pfB, onesf, SB, 0, 0, 0);

#pragma unroll
            for (int i = 0; i < 4; i++) {
                const int d = i * 16 + l15;
                const int x4 = (d & 30) * 4;
                const int bi = d * 128;
                const ushort4 v1 = *(const ushort4*)(Vs + bi + (((s * 8 + quad) * 4) ^ x4));
                const ushort4 v2 = *(const ushort4*)(Vs + bi + (((s * 8 + 4 + quad) * 4) ^ x4));
                bf16x8 vc;
                *(ushort4*)&vc = v1;
                *((ushort4*)&vc + 1) = v2;
                OA[i] = __builtin_amdgcn_mfma_f32_16x16x32_bf16(pfA, vc, OA[i], 0, 0, 0);
                OB[i] = __builtin_amdgcn_mfma_f32_16x16x32_bf16(pfB, vc, OB[i], 0, 0, 0);
            }
        }
    }

    float liA[4], liB[4];
#pragma unroll
    for (int r = 0; r < 4; r++) {
        liA[r] = 1.0f / SA[r];
        liB[r] = 1.0f / SB[r];
    }

    const int b = bh >> 4, h = bh & 15;
#pragma unroll
    for (int i = 0; i < 4; i++)
#pragma unroll
        for (int r = 0; r < 4; r++) {
            const int qa = q0w + quad * 4 + r;
            Oout[((size_t)b * Ll + qa) * Dd + h * DK + i * 16 + l15] = f2bf(OA[i][r] * liA[r]);
            Oout[((size_t)b * Ll + qa + 16) * Dd + h * DK + i * 16 + l15] = f2bf(OB[i][r] * liB[r]);
        }
}

// ---------------- output projection GEMM (R6 64x128, XCD-affine 1D grid) ----------------
// 1D grid 512; flat = xcd + 8*bcol + 64*slot, brow group g = slot*8 + xcd (0..63).
__global__ __launch_bounds__(256) void gemm_o(const ushort* __restrict__ A,
                                              const ushort* __restrict__ W,
                                              const float* __restrict__ bias,
                                              float* __restrict__ Out) {
    __shared__ __align__(16) ushort As[64 * 32];
    __shared__ __align__(16) ushort Bs[128 * 32];
    const int fl = blockIdx.x;
    const int xcd = fl & 7, bcoli = (fl >> 3) & 7, slot = fl >> 6;
    const int g = slot * 8 + xcd;  // brow group 0..63
    const int t = threadIdx.x;
    const int wave = t >> 6, lane = t & 63;
    const int quad = lane >> 4, l15 = lane & 15;
    const int brow = g * 64, bcol = bcoli * 128;
    const int wr = (wave >> 1) * 32, wc = (wave & 1) * 64;
    const int gr = wave * 16 + (lane >> 2);
    const int gc = (lane & 3) * 8;

    f32x4 acc[2][4] = {};

    for (int k0 = 0; k0 < Kk; k0 += 32) {
        __syncthreads();
        glds16(A + (size_t)(brow + gr) * Kk + k0 + gc,      As + wave * 512);
        glds16(W + (size_t)(bcol + gr) * Kk + k0 + gc,      Bs + wave * 512);
        glds16(W + (size_t)(bcol + 64 + gr) * Kk + k0 + gc, Bs + 2048 + wave * 512);
        __syncthreads();

        bf16x8 af[2], bfr[4];
#pragma unroll
        for (int i = 0; i < 2; i++)
            af[i] = *(const bf16x8*)(As + (wr + i * 16 + l15) * 32 + quad * 8);
#pragma unroll
        for (int j = 0; j < 4; j++)
            bfr[j] = *(const bf16x8*)(Bs + (wc + j * 16 + l15) * 32 + quad * 8);
#pragma unroll
        for (int i = 0; i < 2; i++)
#pragma unroll
            for (int j = 0; j < 4; j++)
                acc[i][j] = __builtin_amdgcn_mfma_f32_16x16x32_bf16(af[i], bfr[j], acc[i][j], 0, 0, 0);
    }

#pragma unroll
    for (int i = 0; i < 2; i++)
#pragma unroll
        for (int j = 0; j < 4; j++) {
            const int n = bcol + wc + j * 16 + l15;
            const float bv = bias[n];
#pragma unroll
            for (int r = 0; r < 4; r++) {
                const int m = brow + wr + i * 16 + quad * 4 + r;
                Out[(size_t)m * Nn + n] = acc[i][j][r] + bv;
            }
        }
}

// ---------------- launch ----------------
extern "C" void kernel_launch(void* const* d_in, const int* in_sizes, int n_in,
                              void* d_out, int out_size, void* d_ws, size_t ws_size,
                              hipStream_t stream) {
    const float* query = (const float*)d_in[0];
    const float* key   = (const float*)d_in[1];
    const float* value = (const float*)d_in[2];
    const float* Wq = (const float*)d_in[3];
    const float* bq = (const float*)d_in[4];
    const float* Wk = (const float*)d_in[5];
    const float* bk = (const float*)d_in[6];
    const float* Wv = (const float*)d_in[7];
    const float* bv = (const float*)d_in[8];
    const float* Wo = (const float*)d_in[9];
    const float* bo = (const float*)d_in[10];
    const int* masksize = (const int*)d_in[11];

    char* ws = (char*)d_ws;
    const size_t MB = 1024 * 1024;
    ushort* qb  = (ushort*)(ws + 0 * MB);
    ushort* kbf = (ushort*)(ws + 8 * MB);
    ushort* vbf = (ushort*)(ws + 16 * MB);
    ushort* wqb = (ushort*)(ws + 24 * MB);
    ushort* wkb = (ushort*)(ws + 26 * MB);
    ushort* wvb = (ushort*)(ws + 28 * MB);
    ushort* wob = (ushort*)(ws + 30 * MB);
    ushort* Qp  = (ushort*)(ws + 32 * MB);  // [BH, L, 64], pre-scaled by 0.125*log2e
    ushort* Kp  = (ushort*)(ws + 40 * MB);  // [BH, L, 64]
    ushort* Vt  = (ushort*)(ws + 48 * MB);  // [BH, 64, L]
    ushort* AO  = (ushort*)(ws + 56 * MB);  // [4096, 1024]

    cast_all<<<16384, 256, 0, stream>>>(query, key, value, Wq, Wk, Wv, Wo,
                                        qb, kbf, vbf, wqb, wkb, wvb, wob);

    gemm_qkv<<<768, 256, 0, stream>>>(qb, kbf, vbf,
                                      wqb, wkb, wvb,
                                      bq, bk, bv,
                                      Qp, Kp, Vt);

    attn_kernel<<<512, 256, 0, stream>>>(Qp, Kp, Vt, AO, masksize);

    gemm_o<<<512, 256, 0, stream>>>(AO, wob, bo, (float*)d_out);
}